// Round 2
// baseline (13546.980 us; speedup 1.0000x reference)
//
#include <hip/hip_runtime.h>
#include <hip/hip_cooperative_groups.h>

namespace cg = cooperative_groups;

#define NB 32
#define NT 128
#define NU 768
#define ND 768

__device__ __forceinline__ float fast_exp2(float x) {
#if __has_builtin(__builtin_amdgcn_exp2f)
  return __builtin_amdgcn_exp2f(x);
#else
  return exp2f(x);
#endif
}

// x[B,T,D] -> xT[T,D,B]
__global__ void transpose_x_kernel(const float* __restrict__ x, float* __restrict__ xT) {
  __shared__ float tile[32][33];
  const int t  = blockIdx.x;
  const int d0 = blockIdx.y * 32;
  const int lo = threadIdx.x & 31;
  const int hi = threadIdx.x >> 5;
#pragma unroll
  for (int bb = hi; bb < 32; bb += 8)
    tile[bb][lo] = x[((size_t)bb * NT + t) * ND + d0 + lo];
  __syncthreads();
#pragma unroll
  for (int dd = hi; dd < 32; dd += 8)
    xT[((size_t)t * ND + d0 + dd) * NB + lo] = tile[lo][dd];
}

// h0[B,U] -> hT[U,B]
__global__ void init_h_kernel(const float* __restrict__ h0, float* __restrict__ hT) {
  int i = blockIdx.x * 256 + threadIdx.x;
  if (i < NU * NB) hT[i] = h0[(i & 31) * NU + (i >> 5)];
}

__global__ void __launch_bounds__(256, 3)
rnn_fused_kernel(const float* __restrict__ xT,
                 const float* __restrict__ wk,    // kernel [U,D]
                 const float* __restrict__ wrk,   // recurrent_kernel [U,U]
                 const float* __restrict__ wak,   // attention_kernel [U,D]
                 const float* __restrict__ wrak,  // recurrent_attention_kernel [U,U]
                 const float* __restrict__ bias,
                 const float* __restrict__ gpa,
                 const float* __restrict__ gpra,
                 float* __restrict__ hA,
                 float* __restrict__ hB,
                 float* __restrict__ out)
{
  const int u   = blockIdx.x;
  const int tid = threadIdx.x;
  const int b   = tid & 31;
  const int c   = tid >> 5;        // 0..7
  const int d0  = c * (ND / 8);    // 96-wide chunk

  __shared__ float s_ak[ND], s_k[ND], s_rak[ND], s_rk[ND];
  __shared__ float red[6][4][32];

  for (int i = tid; i < ND; i += 256) {
    s_ak[i]  = wak [(size_t)u * ND + i];
    s_k [i]  = wk  [(size_t)u * ND + i];
    s_rak[i] = wrak[(size_t)u * NU + i];
    s_rk[i]  = wrk [(size_t)u * NU + i];
  }
  const float bias_u = bias[u];
  const float ga  = 1.0f / (1.0f + __expf(-gpa[0]));
  const float gra = 1.0f / (1.0f + __expf(-gpra[0]));
  __syncthreads();

  cg::grid_group grid = cg::this_grid();

  const float* hcur = hA;
  float* hnext = hB;
  const float LOG2E = 1.4426950408889634f;

  for (int t = 0; t < NT; ++t) {
    const float hu = hcur[u * NB + b];   // h[b][u], broadcast over c
    const float hs = hu * LOG2E;

    // ---- input cross-attention half: reduce over d in [d0, d0+96) ----
    float s_a = 0.f, n_a = 0.f, l_a = 0.f;
    {
      const float* xp = xT + ((size_t)t * ND + d0) * NB + b;
#pragma unroll 4
      for (int k = 0; k < ND / 8; ++k) {
        float av = s_ak[d0 + k];
        float kv = s_k [d0 + k];
        float xv = xp[k * NB];
        float e  = fast_exp2(hs * xv * av);
        float kx = kv * xv;
        s_a += e;
        l_a += kx;
        n_a = fmaf(e, kx, n_a);
      }
    }
    // ---- recurrent self-attention half: reduce over v in [d0, d0+96) ----
    float s_r = 0.f, n_r = 0.f, l_r = 0.f;
    {
      const float* hp = hcur + d0 * NB + b;
#pragma unroll 4
      for (int k = 0; k < ND / 8; ++k) {
        float av = s_rak[d0 + k];
        float kv = s_rk [d0 + k];
        float hv = hp[k * NB];
        float e  = fast_exp2(hs * hv * av);
        float kh = kv * hv;
        s_r += e;
        l_r += kh;
        n_r = fmaf(e, kh, n_r);
      }
    }

    // ---- reduce 8 chunks: pair-combine within wave, then 4 waves via LDS ----
    float v0 = s_a + __shfl_xor(s_a, 32);
    float v1 = n_a + __shfl_xor(n_a, 32);
    float v2 = l_a + __shfl_xor(l_a, 32);
    float v3 = s_r + __shfl_xor(s_r, 32);
    float v4 = n_r + __shfl_xor(n_r, 32);
    float v5 = l_r + __shfl_xor(l_r, 32);
    const int w = tid >> 6;
    if ((tid & 63) < 32) {
      red[0][w][b] = v0; red[1][w][b] = v1; red[2][w][b] = v2;
      red[3][w][b] = v3; red[4][w][b] = v4; red[5][w][b] = v5;
    }
    __syncthreads();
    if (tid < 32) {
      float r0 = red[0][0][b] + red[0][1][b] + red[0][2][b] + red[0][3][b];
      float r1 = red[1][0][b] + red[1][1][b] + red[1][2][b] + red[1][3][b];
      float r2 = red[2][0][b] + red[2][1][b] + red[2][2][b] + red[2][3][b];
      float r3 = red[3][0][b] + red[3][1][b] + red[3][2][b] + red[3][3][b];
      float r4 = red[4][0][b] + red[4][1][b] + red[4][2][b] + red[4][3][b];
      float r5 = red[5][0][b] + red[5][1][b] + red[5][2][b] + red[5][3][b];
      float hh = r2 + ga * (r1 / r0) + bias_u;
      float o  = tanhf(hh + r5 + gra * (r4 / r3));
      hnext[u * NB + b] = o;
      out[((size_t)b * NT + t) * NU + u] = o;
    }
    grid.sync();
    const float* tmp = hcur; hcur = hnext; hnext = (float*)tmp;
  }
}

extern "C" void kernel_launch(void* const* d_in, const int* in_sizes, int n_in,
                              void* d_out, int out_size, void* d_ws, size_t ws_size,
                              hipStream_t stream) {
  const float* x    = (const float*)d_in[0];
  const float* h0   = (const float*)d_in[1];
  const float* wk   = (const float*)d_in[2];
  const float* wrk  = (const float*)d_in[3];
  const float* wak  = (const float*)d_in[4];
  const float* wrak = (const float*)d_in[5];
  const float* bias = (const float*)d_in[6];
  const float* gpa  = (const float*)d_in[7];
  const float* gpra = (const float*)d_in[8];
  float* out = (float*)d_out;

  float* xT = (float*)d_ws;
  float* hA = (float*)((char*)d_ws + (size_t)NT * ND * NB * sizeof(float));
  float* hB = hA + NU * NB;

  transpose_x_kernel<<<dim3(NT, ND / 32), 256, 0, stream>>>(x, xT);
  init_h_kernel<<<(NU * NB + 255) / 256, 256, 0, stream>>>(h0, hA);

  void* args[] = { (void*)&xT, (void*)&wk, (void*)&wrk, (void*)&wak, (void*)&wrak,
                   (void*)&bias, (void*)&gpa, (void*)&gpra,
                   (void*)&hA, (void*)&hB, (void*)&out };
  hipLaunchCooperativeKernel(reinterpret_cast<void*>(rnn_fused_kernel),
                             dim3(NU), dim3(256), args, 0u, stream);
}

// Round 3
// 1996.892 us; speedup vs baseline: 6.7840x; 6.7840x over previous
//
#include <hip/hip_runtime.h>

#define NB 32
#define NT 128
#define NU 768
#define ND 768
#define UPB 3
#define NBLK (NU / UPB)   // 256 blocks, one per CU
#define NTHR (256 * UPB)  // 768 threads

#define AGENT __HIP_MEMORY_SCOPE_AGENT

__device__ __forceinline__ float fexp2(float x) { return __builtin_amdgcn_exp2f(x); }
__device__ __forceinline__ float frcp(float x)  { return __builtin_amdgcn_rcpf(x); }

// x[B,T,D] -> xT[T,D,B]
__global__ void transpose_x_kernel(const float* __restrict__ x, float* __restrict__ xT) {
  __shared__ float tile[32][33];
  const int t  = blockIdx.x;
  const int d0 = blockIdx.y * 32;
  const int lo = threadIdx.x & 31;
  const int hi = threadIdx.x >> 5;
#pragma unroll
  for (int bb = hi; bb < 32; bb += 8)
    tile[bb][lo] = x[((size_t)bb * NT + t) * ND + d0 + lo];
  __syncthreads();
#pragma unroll
  for (int dd = hi; dd < 32; dd += 8)
    xT[((size_t)t * ND + d0 + dd) * NB + lo] = tile[lo][dd];
}

// h0[B,U] -> hT[U,B], and zero the barrier flags
__global__ void init_h_kernel(const float* __restrict__ h0, float* __restrict__ hT,
                              unsigned int* __restrict__ flags) {
  int i = blockIdx.x * 256 + threadIdx.x;
  if (i < NU * NB) hT[i] = h0[(i & 31) * NU + (i >> 5)];
  if (i < NBLK) flags[i] = 0u;
}

// outT[T,U,B] -> out[B,T,U]
__global__ void transpose_out_kernel(const float* __restrict__ outT, float* __restrict__ out) {
  __shared__ float tile[32][33];
  const int t  = blockIdx.x;
  const int u0 = blockIdx.y * 32;
  const int lo = threadIdx.x & 31;
  const int hi = threadIdx.x >> 5;
#pragma unroll
  for (int uu = hi; uu < 32; uu += 8)
    tile[uu][lo] = outT[((size_t)t * NU + u0 + uu) * NB + lo];
  __syncthreads();
#pragma unroll
  for (int bb = hi; bb < 32; bb += 8)
    out[((size_t)bb * NT + t) * NU + u0 + lo] = tile[lo][bb];
}

__global__ void __launch_bounds__(NTHR)
rnn_fused_kernel(const float* __restrict__ xT,
                 const float* __restrict__ wk,    // kernel [U,D]
                 const float* __restrict__ wrk,   // recurrent_kernel [U,U]
                 const float* __restrict__ wak,   // attention_kernel [U,D]
                 const float* __restrict__ wrak,  // recurrent_attention_kernel [U,U]
                 const float* __restrict__ bias,
                 const float* __restrict__ gpa,
                 const float* __restrict__ gpra,
                 float* hA, float* hB,
                 float* __restrict__ outT,
                 unsigned int* flags)
{
  const int tid  = threadIdx.x;
  const int uloc = tid >> 8;        // 0..2
  const int lt   = tid & 255;       // rank within u-group
  const int b    = lt & 31;
  const int c    = lt >> 5;         // 0..7
  const int d0   = c * 96;
  const int u    = blockIdx.x * UPB + uloc;

  __shared__ float2 s2a[UPB][ND];           // (ak, k)   12 KB per u
  __shared__ float2 s2r[UPB][ND];           // (rak, rk)
  __shared__ float  red[UPB][6][4][32];     // 9 KB

  // stage weights (coalesced: lane = tid over d)
#pragma unroll
  for (int j = 0; j < UPB; ++j) {
    const int ug = blockIdx.x * UPB + j;
    s2a[j][tid] = make_float2(wak [(size_t)ug * ND + tid], wk [(size_t)ug * ND + tid]);
    s2r[j][tid] = make_float2(wrak[(size_t)ug * NU + tid], wrk[(size_t)ug * NU + tid]);
  }
  const float bias_u = bias[u];
  const float ga  = 1.0f / (1.0f + __expf(-gpa[0]));
  const float gra = 1.0f / (1.0f + __expf(-gpra[0]));
  __syncthreads();

  float* hcur  = hA;
  float* hnext = hB;
  const float LOG2E = 1.4426950408889634f;

  for (int t = 0; t < NT; ++t) {
    const float hu = __hip_atomic_load(&hcur[u * NB + b], __ATOMIC_RELAXED, AGENT);
    const float hs = hu * LOG2E;

    // ---- input cross-attention: reduce d in [d0, d0+96) ----
    float s_a = 0.f, n_a = 0.f, l_a = 0.f;
    {
      const float*  xp = xT + ((size_t)t * ND + d0) * NB + b;
      const float2* wa = &s2a[uloc][d0];
#pragma unroll 8
      for (int k = 0; k < 96; ++k) {
        float2 w2 = wa[k];
        float  xv = xp[k * NB];
        float  e  = fexp2(hs * xv * w2.x);
        float  kx = w2.y * xv;
        s_a += e;
        l_a += kx;
        n_a = fmaf(e, kx, n_a);
      }
    }
    // ---- recurrent self-attention: reduce v in [d0, d0+96) ----
    float s_r = 0.f, n_r = 0.f, l_r = 0.f;
    {
      float*        hp = hcur + (size_t)d0 * NB + b;
      const float2* wr = &s2r[uloc][d0];
#pragma unroll 8
      for (int k = 0; k < 96; ++k) {
        float2 w2 = wr[k];
        float  hv = __hip_atomic_load(&hp[k * NB], __ATOMIC_RELAXED, AGENT);
        float  e  = fexp2(hs * hv * w2.x);
        float  kh = w2.y * hv;
        s_r += e;
        l_r += kh;
        n_r = fmaf(e, kh, n_r);
      }
    }

    // ---- reduce 8 chunks: pair-combine (c ^ 1) within wave, 4 waves via LDS ----
    float v0 = s_a + __shfl_xor(s_a, 32);
    float v1 = n_a + __shfl_xor(n_a, 32);
    float v2 = l_a + __shfl_xor(l_a, 32);
    float v3 = s_r + __shfl_xor(s_r, 32);
    float v4 = n_r + __shfl_xor(n_r, 32);
    float v5 = l_r + __shfl_xor(l_r, 32);
    const int w = (tid >> 6) & 3;
    if ((tid & 63) < 32) {
      red[uloc][0][w][b] = v0; red[uloc][1][w][b] = v1; red[uloc][2][w][b] = v2;
      red[uloc][3][w][b] = v3; red[uloc][4][w][b] = v4; red[uloc][5][w][b] = v5;
    }
    __syncthreads();

    if (lt < 32) {
      float r0 = red[uloc][0][0][b] + red[uloc][0][1][b] + red[uloc][0][2][b] + red[uloc][0][3][b];
      float r1 = red[uloc][1][0][b] + red[uloc][1][1][b] + red[uloc][1][2][b] + red[uloc][1][3][b];
      float r2 = red[uloc][2][0][b] + red[uloc][2][1][b] + red[uloc][2][2][b] + red[uloc][2][3][b];
      float r3 = red[uloc][3][0][b] + red[uloc][3][1][b] + red[uloc][3][2][b] + red[uloc][3][3][b];
      float r4 = red[uloc][4][0][b] + red[uloc][4][1][b] + red[uloc][4][2][b] + red[uloc][4][3][b];
      float r5 = red[uloc][5][0][b] + red[uloc][5][1][b] + red[uloc][5][2][b] + red[uloc][5][3][b];
      float hh = r2 + bias_u + ga * (r1 * frcp(r0));
      float z  = hh + r5 + gra * (r4 * frcp(r3));
      // tanh(z) = 1 - 2/(exp2(z*2*log2e)+1)
      float ex = fexp2(z * 2.8853900817779268f);
      float o  = 1.0f - 2.0f * frcp(ex + 1.0f);
      __hip_atomic_store(&hnext[u * NB + b], o, __ATOMIC_RELAXED, AGENT);
      outT[((size_t)t * NU + u) * NB + b] = o;
    }

    if (t != NT - 1) {
      // h stores (sc1, LLC-coherent) must complete before this block's flag is seen.
      asm volatile("s_waitcnt vmcnt(0)" ::: "memory");
      __syncthreads();   // every u-group's storing wave has drained its vmem
      if (tid == 0)
        __hip_atomic_store(&flags[blockIdx.x], (unsigned)(t + 1), __ATOMIC_RELAXED, AGENT);
      if (tid < NBLK) {
        const unsigned tgt = (unsigned)(t + 1);
        while (__hip_atomic_load(&flags[tid], __ATOMIC_RELAXED, AGENT) < tgt)
          __builtin_amdgcn_s_sleep(2);
      }
      __syncthreads();
    }
    { float* tmp = hcur; hcur = hnext; hnext = tmp; }
  }
}

extern "C" void kernel_launch(void* const* d_in, const int* in_sizes, int n_in,
                              void* d_out, int out_size, void* d_ws, size_t ws_size,
                              hipStream_t stream) {
  const float* x    = (const float*)d_in[0];
  const float* h0   = (const float*)d_in[1];
  const float* wk   = (const float*)d_in[2];
  const float* wrk  = (const float*)d_in[3];
  const float* wak  = (const float*)d_in[4];
  const float* wrak = (const float*)d_in[5];
  const float* bias = (const float*)d_in[6];
  const float* gpa  = (const float*)d_in[7];
  const float* gpra = (const float*)d_in[8];
  float* out = (float*)d_out;

  float* xT   = (float*)d_ws;                       // 12.58 MB
  float* outT = xT + (size_t)NT * ND * NB;          // 12.58 MB
  float* hA   = outT + (size_t)NT * NU * NB;        // 96 KB
  float* hB   = hA + NU * NB;                       // 96 KB
  unsigned int* flags = (unsigned int*)(hB + NU * NB);

  transpose_x_kernel<<<dim3(NT, ND / 32), 256, 0, stream>>>(x, xT);
  init_h_kernel<<<(NU * NB + 255) / 256, 256, 0, stream>>>(h0, hA, flags);
  rnn_fused_kernel<<<NBLK, NTHR, 0, stream>>>(xT, wk, wrk, wak, wrak, bias, gpa, gpra,
                                              hA, hB, outT, flags);
  transpose_out_kernel<<<dim3(NT, NU / 32), 256, 0, stream>>>(outT, out);
}